// Round 8
// baseline (103.023 us; speedup 1.0000x reference)
//
#include <hip/hip_runtime.h>
#include <hip/hip_bf16.h>

typedef float f32x4 __attribute__((ext_vector_type(4)));
typedef short s16x8 __attribute__((ext_vector_type(8)));

#define D_DIM 4096
#define NT 24            // 16-wide col tiles
#define NBODY 32         // bodies per block (BK=64 each, K-half = 2048)
#define BM 32            // rows per block
// ws byte offsets
#define PART_OFF (4u << 20)                      // part[2][256][32*384] f32 = 24 MiB
#define SINW_OFF ((4u << 20) + 25165824u)        // sinws[2][8192] f32 = 64 KiB

__device__ __forceinline__ unsigned short f2bf(float f) {
    unsigned u = __float_as_uint(f);
    u += 0x7fffu + ((u >> 16) & 1u);   // RNE
    return (unsigned short)(u >> 16);
}

__global__ __launch_bounds__(64) void reg_init_kernel(const float* __restrict__ C,
                                                      const float* __restrict__ Csin,
                                                      float* __restrict__ reg_out) {
    if (threadIdx.x == 0)
        reg_out[0] = 0.05f * (fabsf(C[0]) + fabsf(C[1]) + fabsf(C[2]) + fabsf(Csin[0]));
}

// Build W [4096 x 384] bf16, MFMA B-fragment-packed, slab-contiguous:
// chunk = (k>>5)*NT + (n>>4); lane = ((k&31)>>3)*16 | (n&15); j = k&7.
__global__ __launch_bounds__(64) void build_w_kernel(const float* __restrict__ U1,
                                                     const float* __restrict__ U2,
                                                     const float* __restrict__ U3,
                                                     unsigned short* __restrict__ W,
                                                     float* __restrict__ reg_out) {
    const int ks = blockIdx.x / NT;
    const int ct = blockIdx.x % NT;
    const int l  = threadIdx.x;
    const int n  = ct * 16 + (l & 15);
    const int kb = ks * 32 + ((l >> 4) << 3);

    const float* src;
    float scale;
    if (n < 64)       { src = U1 + n;                  scale = 0.01f / 262144.f; }
    else if (n < 128) { src = U2 + (n - 64);           scale = 0.01f / 524288.f; }
    else if (n < 192) { src = U2 + 262144 + (n - 128); scale = 0.01f / 524288.f; }
    else if (n < 256) { src = U3 + (n - 192);          scale = 0.01f / 786432.f; }
    else if (n < 320) { src = U3 + 262144 + (n - 256); scale = 0.01f / 786432.f; }
    else              { src = U3 + 524288 + (n - 320); scale = 0.01f / 786432.f; }

    unsigned short h[8];
    float sabs = 0.f;
#pragma unroll
    for (int j = 0; j < 8; ++j) {
        float u = src[(size_t)(kb + j) * 64];
        sabs += fabsf(u);
        h[j] = f2bf(u);
    }
    uint4 pk;
    pk.x = (unsigned)h[0] | ((unsigned)h[1] << 16);
    pk.y = (unsigned)h[2] | ((unsigned)h[3] << 16);
    pk.z = (unsigned)h[4] | ((unsigned)h[5] << 16);
    pk.w = (unsigned)h[6] | ((unsigned)h[7] << 16);
    *(uint4*)(W + ((size_t)blockIdx.x * 64 + l) * 8) = pk;

    sabs *= scale;
#pragma unroll
    for (int off = 32; off >= 1; off >>= 1)
        sabs += __shfl_xor(sabs, off, 64);
    if (l == 0) atomicAdd(reg_out, sabs);
}

// grid 512 = (rb 0..255) x (kh 0..1); 512 thr = 8 waves = 8 cg (3 col-tiles).
// Block: 32 rows x 384 cols x 2048 k, 32 bodies of BK=64. 2 blocks/CU = two
// independent barrier groups overlap phases. Wave/body: 4 ds_read_b128 A-frags
// + 6 B-frags (2-deep reg rotation from L2-resident frag-packed W) + 12 MFMA.
// X 3-deep reg rotation; A slab (32x64 bf16, 4KB) staged by all 512 thr,
// double-buffered. Raw s_barrier + lgkmcnt-only drain (loads cross barriers).
__global__ __launch_bounds__(512, 4) void poly_main_kernel(const float* __restrict__ X,
                                                           const unsigned short* __restrict__ W,
                                                           float* __restrict__ part,
                                                           float* __restrict__ sinws) {
    __shared__ __align__(16) char pool[8192 + 128];   // A bufs [2][4096] + sinrow

    const int t    = threadIdx.x;
    const int lane = t & 63;
    const int wv   = t >> 6;          // 0..7
    const int ct0  = wv * 3;
    const int rb   = blockIdx.x >> 1;
    const int kh   = blockIdx.x & 1;
    const int row0 = rb * BM;

    // A staging: thread -> (row srow, 4 k's at k4) of each 32x64 body-slab
    const int srow = t >> 4;              // 0..31
    const int k4   = (t & 15) << 2;       // 0..60
    const float* xp = X + (size_t)(row0 + srow) * D_DIM + kh * 2048 + k4;
    const int awfrag = (k4 >> 5) * 2048 + (srow >> 4) * 1024
                     + (((((k4 & 31) >> 3) << 4) | (srow & 15)) * 16) + ((k4 & 7) << 1);

    const s16x8* __restrict__ Wh = (const s16x8*)W + (size_t)kh * 64 * NT * 64;

    f32x4 acc00{}, acc01{}, acc02{}, acc10{}, acc11{}, acc12{};
    float sinacc = 0.f;
    f32x4 xw{}, xa{}, xb{};

    // ---- prologue: stage body 0 into buf0; X 3-deep; B set A <- body 0 ----
    {
        f32x4 x0 = *(const f32x4*)xp;
        sinacc += __sinf(x0.x) + __sinf(x0.y) + __sinf(x0.z) + __sinf(x0.w);
        short4 h;
        h.x = (short)f2bf(x0.x); h.y = (short)f2bf(x0.y);
        h.z = (short)f2bf(x0.z); h.w = (short)f2bf(x0.w);
        *(short4*)(pool + awfrag) = h;
        xw = *(const f32x4*)(xp + 64);    // body 1 (staged @ d=0)
        xa = *(const f32x4*)(xp + 128);   // body 2 (staged @ d=1)
        xb = *(const f32x4*)(xp + 192);   // body 3 (staged @ d=2)
    }
    s16x8 bA0 = Wh[((size_t)0 * NT + ct0 + 0) * 64 + lane];
    s16x8 bA1 = Wh[((size_t)0 * NT + ct0 + 1) * 64 + lane];
    s16x8 bA2 = Wh[((size_t)0 * NT + ct0 + 2) * 64 + lane];
    s16x8 bA3 = Wh[((size_t)1 * NT + ct0 + 0) * 64 + lane];
    s16x8 bA4 = Wh[((size_t)1 * NT + ct0 + 1) * 64 + lane];
    s16x8 bA5 = Wh[((size_t)1 * NT + ct0 + 2) * 64 + lane];
    s16x8 bB0{}, bB1{}, bB2{}, bB3{}, bB4{}, bB5{};
    asm volatile("s_waitcnt lgkmcnt(0)" ::: "memory");
    __builtin_amdgcn_s_barrier();
    __builtin_amdgcn_sched_barrier(0);

// BODY d: stage body d+1 from XW; reload XW <- body d+4 (used @ d+3);
// prefetch B set P <- body d+1 (used @ d+1); compute body d with set U.
#define BODY(d_, U0, U1, U2, U3, U4, U5, P0, P1, P2, P3, P4, P5, XW)            \
    {                                                                           \
        const int d__ = (d_);                                                   \
        if (d__ + 1 < NBODY) {                                                  \
            sinacc += __sinf(XW.x) + __sinf(XW.y)                               \
                    + __sinf(XW.z) + __sinf(XW.w);                              \
            short4 h_;                                                          \
            h_.x = (short)f2bf(XW.x); h_.y = (short)f2bf(XW.y);                 \
            h_.z = (short)f2bf(XW.z); h_.w = (short)f2bf(XW.w);                 \
            *(short4*)(pool + ((d__ + 1) & 1) * 4096 + awfrag) = h_;            \
        }                                                                       \
        int sl_ = d__ + 4; if (sl_ > NBODY - 1) sl_ = NBODY - 1;                \
        XW = *(const f32x4*)(xp + (size_t)sl_ * 64);                            \
        int sp_ = d__ + 1; if (sp_ > NBODY - 1) sp_ = NBODY - 1;                \
        P0 = Wh[((size_t)(2 * sp_ + 0) * NT + ct0 + 0) * 64 + lane];            \
        P1 = Wh[((size_t)(2 * sp_ + 0) * NT + ct0 + 1) * 64 + lane];            \
        P2 = Wh[((size_t)(2 * sp_ + 0) * NT + ct0 + 2) * 64 + lane];            \
        P3 = Wh[((size_t)(2 * sp_ + 1) * NT + ct0 + 0) * 64 + lane];            \
        P4 = Wh[((size_t)(2 * sp_ + 1) * NT + ct0 + 1) * 64 + lane];            \
        P5 = Wh[((size_t)(2 * sp_ + 1) * NT + ct0 + 2) * 64 + lane];            \
        const int ab_ = (d__ & 1) * 4096;                                       \
        s16x8 a00_ = *(const s16x8*)(pool + ab_ +        lane * 16);            \
        s16x8 a10_ = *(const s16x8*)(pool + ab_ + 1024 + lane * 16);            \
        s16x8 a01_ = *(const s16x8*)(pool + ab_ + 2048 + lane * 16);            \
        s16x8 a11_ = *(const s16x8*)(pool + ab_ + 3072 + lane * 16);            \
        asm volatile("s_waitcnt lgkmcnt(0)" ::: "memory");                      \
        __builtin_amdgcn_sched_barrier(0);                                      \
        __builtin_amdgcn_s_setprio(1);                                          \
        acc00 = __builtin_amdgcn_mfma_f32_16x16x32_bf16(a00_, U0, acc00, 0, 0, 0); \
        acc01 = __builtin_amdgcn_mfma_f32_16x16x32_bf16(a00_, U1, acc01, 0, 0, 0); \
        acc02 = __builtin_amdgcn_mfma_f32_16x16x32_bf16(a00_, U2, acc02, 0, 0, 0); \
        acc10 = __builtin_amdgcn_mfma_f32_16x16x32_bf16(a10_, U0, acc10, 0, 0, 0); \
        acc11 = __builtin_amdgcn_mfma_f32_16x16x32_bf16(a10_, U1, acc11, 0, 0, 0); \
        acc12 = __builtin_amdgcn_mfma_f32_16x16x32_bf16(a10_, U2, acc12, 0, 0, 0); \
        acc00 = __builtin_amdgcn_mfma_f32_16x16x32_bf16(a01_, U3, acc00, 0, 0, 0); \
        acc01 = __builtin_amdgcn_mfma_f32_16x16x32_bf16(a01_, U4, acc01, 0, 0, 0); \
        acc02 = __builtin_amdgcn_mfma_f32_16x16x32_bf16(a01_, U5, acc02, 0, 0, 0); \
        acc10 = __builtin_amdgcn_mfma_f32_16x16x32_bf16(a11_, U3, acc10, 0, 0, 0); \
        acc11 = __builtin_amdgcn_mfma_f32_16x16x32_bf16(a11_, U4, acc11, 0, 0, 0); \
        acc12 = __builtin_amdgcn_mfma_f32_16x16x32_bf16(a11_, U5, acc12, 0, 0, 0); \
        __builtin_amdgcn_s_setprio(0);                                          \
        __builtin_amdgcn_s_barrier();                                           \
        __builtin_amdgcn_sched_barrier(0);                                      \
    }

    // 6-body unroll aligns 2-set B rotation with 3-reg X rotation.
    for (int e = 0; e < 5; ++e) {
        const int d0 = 6 * e;
        BODY(d0 + 0, bA0, bA1, bA2, bA3, bA4, bA5, bB0, bB1, bB2, bB3, bB4, bB5, xw);
        BODY(d0 + 1, bB0, bB1, bB2, bB3, bB4, bB5, bA0, bA1, bA2, bA3, bA4, bA5, xa);
        BODY(d0 + 2, bA0, bA1, bA2, bA3, bA4, bA5, bB0, bB1, bB2, bB3, bB4, bB5, xb);
        BODY(d0 + 3, bB0, bB1, bB2, bB3, bB4, bB5, bA0, bA1, bA2, bA3, bA4, bA5, xw);
        BODY(d0 + 4, bA0, bA1, bA2, bA3, bA4, bA5, bB0, bB1, bB2, bB3, bB4, bB5, xa);
        BODY(d0 + 5, bB0, bB1, bB2, bB3, bB4, bB5, bA0, bA1, bA2, bA3, bA4, bA5, xb);
    }
    BODY(30, bA0, bA1, bA2, bA3, bA4, bA5, bB0, bB1, bB2, bB3, bB4, bB5, xw);
    BODY(31, bB0, bB1, bB2, bB3, bB4, bB5, bA0, bA1, bA2, bA3, bA4, bA5, xa);
#undef BODY

    // ---- epilogue: direct global partial write (no Dmat) ----
    float* pb = part + ((size_t)kh * 256 + rb) * (BM * 384);
    const int lr4 = (lane >> 4) << 2;
    const int lc  = lane & 15;
    const f32x4 accA[2][3] = {{acc00, acc01, acc02}, {acc10, acc11, acc12}};
#pragma unroll
    for (int rf = 0; rf < 2; ++rf)
#pragma unroll
        for (int c = 0; c < 3; ++c) {
            const int col = (ct0 + c) * 16 + lc;
#pragma unroll
            for (int i = 0; i < 4; ++i)
                pb[(size_t)(rf * 16 + lr4 + i) * 384 + col] = accA[rf][c][i];
        }

    sinacc += __shfl_xor(sinacc, 1);
    sinacc += __shfl_xor(sinacc, 2);
    sinacc += __shfl_xor(sinacc, 4);
    sinacc += __shfl_xor(sinacc, 8);
    if ((t & 15) == 0)
        sinws[(size_t)kh * 8192 + row0 + srow] = sinacc;
}

__global__ __launch_bounds__(512) void combine_kernel(const float* __restrict__ part,
                                                      const float* __restrict__ sinws,
                                                      const float* __restrict__ C,
                                                      const float* __restrict__ beta,
                                                      const float* __restrict__ Csin,
                                                      float* __restrict__ out) {
    const int t   = threadIdx.x;
    const int row = blockIdx.x * 32 + (t >> 4);
    const int cc  = t & 15;
    const int rb  = row >> 5;
    const int lr  = row & 31;
    const float* p0 = part + (size_t)rb * (BM * 384) + (size_t)lr * 384;
    const float* p1 = p0 + (size_t)256 * (BM * 384);

    float t1 = 0.f, t2 = 0.f, t3 = 0.f;
#pragma unroll
    for (int rr = 0; rr < 64; rr += 16) {
        const int c = rr + cc;
        const float d1 = p0[c]       + p1[c];
        const float a2 = p0[64 + c]  + p1[64 + c];
        const float b2 = p0[128 + c] + p1[128 + c];
        const float a3 = p0[192 + c] + p1[192 + c];
        const float b3 = p0[256 + c] + p1[256 + c];
        const float c3 = p0[320 + c] + p1[320 + c];
        t1 += d1;
        t2 += a2 * b2;
        t3 += a3 * b3 * c3;
    }
#pragma unroll
    for (int off = 1; off < 16; off <<= 1) {
        t1 += __shfl_xor(t1, off, 16);
        t2 += __shfl_xor(t2, off, 16);
        t3 += __shfl_xor(t3, off, 16);
    }
    if (cc == 0) {
        const float s = sinws[row] + sinws[8192 + row];
        out[row] = beta[0] + C[0] * t1 + C[1] * t2 + C[2] * t3 + Csin[0] * s;
    }
}

extern "C" void kernel_launch(void* const* d_in, const int* in_sizes, int n_in,
                              void* d_out, int out_size, void* d_ws, size_t ws_size,
                              hipStream_t stream) {
    const float* X   = (const float*)d_in[0];
    const float* U1  = (const float*)d_in[1];
    const float* U2  = (const float*)d_in[2];
    const float* U3  = (const float*)d_in[3];
    const float* Cc  = (const float*)d_in[4];
    const float* bet = (const float*)d_in[5];
    const float* Cs  = (const float*)d_in[6];
    float* out = (float*)d_out;

    unsigned short* W = (unsigned short*)d_ws;                 // 3 MiB, frag-packed
    float* part  = (float*)((char*)d_ws + PART_OFF);           // 24 MiB
    float* sinws = (float*)((char*)d_ws + SINW_OFF);           // 64 KiB

    reg_init_kernel<<<1, 64, 0, stream>>>(Cc, Cs, out + 8192);
    build_w_kernel<<<128 * NT, 64, 0, stream>>>(U1, U2, U3, W, out + 8192);
    poly_main_kernel<<<512, 512, 0, stream>>>(X, W, part, sinws);
    combine_kernel<<<256, 512, 0, stream>>>(part, sinws, Cc, bet, Cs, out);
}

// Round 9
// 96.506 us; speedup vs baseline: 1.0675x; 1.0675x over previous
//
#include <hip/hip_runtime.h>
#include <hip/hip_bf16.h>

typedef float f32x4 __attribute__((ext_vector_type(4)));
typedef short s16x8 __attribute__((ext_vector_type(8)));

#define D_DIM 4096
#define NT 24            // 16-wide col tiles (global)
#define BM 128           // rows per block
#define KS 4             // K split (quarters of 1024)
#define NBODY 16         // bodies per block, BK=64
// ws byte offsets (total 28,442,624 B — under proven budget)
#define SINW_OFF 3145728u                 // sinws[4][8192] f32 = 128 KiB
#define PART_OFF 3276800u                 // part[4][8192][384] f16 = 24 MiB
// LDS address swizzle: XOR bank bits [6:4] with bits [9:7]
#define SWZ(a) ((a) ^ ((((a) >> 7) & 7) << 4))

__device__ __forceinline__ unsigned short f2bf(float f) {
    unsigned u = __float_as_uint(f);
    u += 0x7fffu + ((u >> 16) & 1u);   // RNE
    return (unsigned short)(u >> 16);
}

__global__ __launch_bounds__(64) void reg_init_kernel(const float* __restrict__ C,
                                                      const float* __restrict__ Csin,
                                                      float* __restrict__ reg_out) {
    if (threadIdx.x == 0)
        reg_out[0] = 0.05f * (fabsf(C[0]) + fabsf(C[1]) + fabsf(C[2]) + fabsf(Csin[0]));
}

// Build W [4096 x 384] bf16, MFMA B-fragment-packed, slab-contiguous:
// chunk = (k>>5)*NT + (n>>4); lane = ((k&31)>>3)*16 | (n&15); j = k&7.
__global__ __launch_bounds__(64) void build_w_kernel(const float* __restrict__ U1,
                                                     const float* __restrict__ U2,
                                                     const float* __restrict__ U3,
                                                     unsigned short* __restrict__ W,
                                                     float* __restrict__ reg_out) {
    const int ks = blockIdx.x / NT;
    const int ct = blockIdx.x % NT;
    const int l  = threadIdx.x;
    const int n  = ct * 16 + (l & 15);
    const int kb = ks * 32 + ((l >> 4) << 3);

    const float* src;
    float scale;
    if (n < 64)       { src = U1 + n;                  scale = 0.01f / 262144.f; }
    else if (n < 128) { src = U2 + (n - 64);           scale = 0.01f / 524288.f; }
    else if (n < 192) { src = U2 + 262144 + (n - 128); scale = 0.01f / 524288.f; }
    else if (n < 256) { src = U3 + (n - 192);          scale = 0.01f / 786432.f; }
    else if (n < 320) { src = U3 + 262144 + (n - 256); scale = 0.01f / 786432.f; }
    else              { src = U3 + 524288 + (n - 320); scale = 0.01f / 786432.f; }

    unsigned short h[8];
    float sabs = 0.f;
#pragma unroll
    for (int j = 0; j < 8; ++j) {
        float u = src[(size_t)(kb + j) * 64];
        sabs += fabsf(u);
        h[j] = f2bf(u);
    }
    uint4 pk;
    pk.x = (unsigned)h[0] | ((unsigned)h[1] << 16);
    pk.y = (unsigned)h[2] | ((unsigned)h[3] << 16);
    pk.z = (unsigned)h[4] | ((unsigned)h[5] << 16);
    pk.w = (unsigned)h[6] | ((unsigned)h[7] << 16);
    *(uint4*)(W + ((size_t)blockIdx.x * 64 + l) * 8) = pk;

    sabs *= scale;
#pragma unroll
    for (int off = 32; off >= 1; off >>= 1)
        sabs += __shfl_xor(sabs, off, 64);
    if (l == 0) atomicAdd(reg_out, sabs);
}

// grid 256 = (rb 0..63) x (ks 0..3); 512 thr = 8 waves = 2 rg x 4 cg.
// Block: 128 rows x 384 cols x 1024 k (16 bodies of BK=64) -> 1.28 MB/CU VMEM.
// Per body/wave: 12 B-frag loads (L2 W, issued first), 8 A ds_read_b128
// (XOR-swizzled), 48 MFMA (4 rowfrags x 6 coltiles x 2 kslabs). A slab
// (128x64 bf16, 16KB) staged by all 512 thr (2 x ds_write_b128 each),
// double-buffered. Raw s_barrier + lgkmcnt-only drain. f16 partials to ws.
__global__ __launch_bounds__(512, 2) void poly_main_kernel(const float* __restrict__ X,
                                                           const unsigned short* __restrict__ W,
                                                           _Float16* __restrict__ part,
                                                           float* __restrict__ sinws) {
    __shared__ __align__(16) char pool[32768];   // A bufs [2][16384]

    const int t    = threadIdx.x;
    const int lane = t & 63;
    const int wv   = t >> 6;          // 0..7
    const int rg   = wv >> 2;         // 0..1
    const int cg   = wv & 3;          // 0..3
    const int ct0  = cg * 6;          // global col-tile base
    const int rb   = blockIdx.x >> 2;
    const int ks   = blockIdx.x & 3;
    const int row0 = rb * BM;

    // staging: thread -> (row srow, 16 k's at k16) of each 128x64 slab
    const int srow = t >> 2;              // 0..127
    const int k16  = (t & 3) << 4;        // 0,16,32,48
    const float* xp = X + (size_t)(row0 + srow) * D_DIM + ks * 1024 + k16;
    const int kslot_s = k16 >> 5;
    const int ch0     = (k16 & 31) >> 3;  // 0 or 2
    const int fragw   = kslot_s * 8 + (srow >> 4);
    const int aw0 = SWZ(fragw * 1024 + (((ch0 + 0) << 4) | (srow & 15)) * 16);
    const int aw1 = SWZ(fragw * 1024 + (((ch0 + 1) << 4) | (srow & 15)) * 16);

    const s16x8* __restrict__ Wf = (const s16x8*)W;

    f32x4 acc[4][6];
#pragma unroll
    for (int r = 0; r < 4; ++r)
#pragma unroll
        for (int c = 0; c < 6; ++c) acc[r][c] = (f32x4){0.f, 0.f, 0.f, 0.f};
    float sinacc = 0.f;

    f32x4 xA0, xA1, xA2, xA3, xB0, xB1, xB2, xB3;

#define LOADX(S0, S1, S2, S3, slab)                                             \
    { const float* _p = xp + (size_t)(slab) * 64;                               \
      S0 = *(const f32x4*)(_p);      S1 = *(const f32x4*)(_p + 4);              \
      S2 = *(const f32x4*)(_p + 8);  S3 = *(const f32x4*)(_p + 12); }

#define STAGE(buf, S0, S1, S2, S3)                                              \
    {                                                                           \
        sinacc += __sinf(S0.x) + __sinf(S0.y) + __sinf(S0.z) + __sinf(S0.w)     \
                + __sinf(S1.x) + __sinf(S1.y) + __sinf(S1.z) + __sinf(S1.w)     \
                + __sinf(S2.x) + __sinf(S2.y) + __sinf(S2.z) + __sinf(S2.w)     \
                + __sinf(S3.x) + __sinf(S3.y) + __sinf(S3.z) + __sinf(S3.w);    \
        uint4 lo, hi;                                                           \
        lo.x = (unsigned)f2bf(S0.x) | ((unsigned)f2bf(S0.y) << 16);             \
        lo.y = (unsigned)f2bf(S0.z) | ((unsigned)f2bf(S0.w) << 16);             \
        lo.z = (unsigned)f2bf(S1.x) | ((unsigned)f2bf(S1.y) << 16);             \
        lo.w = (unsigned)f2bf(S1.z) | ((unsigned)f2bf(S1.w) << 16);             \
        hi.x = (unsigned)f2bf(S2.x) | ((unsigned)f2bf(S2.y) << 16);             \
        hi.y = (unsigned)f2bf(S2.z) | ((unsigned)f2bf(S2.w) << 16);             \
        hi.z = (unsigned)f2bf(S3.x) | ((unsigned)f2bf(S3.y) << 16);             \
        hi.w = (unsigned)f2bf(S3.z) | ((unsigned)f2bf(S3.w) << 16);             \
        *(uint4*)(pool + (buf) * 16384 + aw0) = lo;                             \
        *(uint4*)(pool + (buf) * 16384 + aw1) = hi;                             \
    }

    // ---- prologue: stage slab 0 into buf0; load X slab 1 ----
    LOADX(xA0, xA1, xA2, xA3, 0);
    STAGE(0, xA0, xA1, xA2, xA3);
    LOADX(xB0, xB1, xB2, xB3, 1);
    asm volatile("s_waitcnt lgkmcnt(0)" ::: "memory");
    __builtin_amdgcn_s_barrier();
    __builtin_amdgcn_sched_barrier(0);

// BODY d: issue B(d) (12 frags, FIFO before X so B's vmcnt skips X); reload
// XL <- slab d+2; stage slab d+1 from XS; ds_read 8 A-frags; lgkm-only drain;
// 48 MFMA; barrier. Loads in flight cross the barrier freely.
#define BODY(d_, XS0, XS1, XS2, XS3, XL0, XL1, XL2, XL3)                        \
    {                                                                           \
        const int d__ = (d_);                                                   \
        const int sb_ = ks * 32 + 2 * d__;                                      \
        s16x8 bb[2][6];                                                         \
        _Pragma("unroll")                                                       \
        for (int kk = 0; kk < 2; ++kk)                                          \
            _Pragma("unroll")                                                   \
            for (int c = 0; c < 6; ++c)                                         \
                bb[kk][c] = Wf[((size_t)(sb_ + kk) * NT + ct0 + c) * 64 + lane];\
        int sl_ = d__ + 2; if (sl_ > NBODY - 1) sl_ = NBODY - 1;                \
        LOADX(XL0, XL1, XL2, XL3, sl_);                                         \
        if (d__ < NBODY - 1) { STAGE((d__ + 1) & 1, XS0, XS1, XS2, XS3); }      \
        const int ab_ = (d__ & 1) * 16384;                                      \
        s16x8 af[2][4];                                                         \
        _Pragma("unroll")                                                       \
        for (int kk = 0; kk < 2; ++kk)                                          \
            _Pragma("unroll")                                                   \
            for (int rf = 0; rf < 4; ++rf)                                      \
                af[kk][rf] = *(const s16x8*)(pool + ab_ +                       \
                    SWZ((kk * 8 + rg * 4 + rf) * 1024 + lane * 16));            \
        asm volatile("s_waitcnt lgkmcnt(0)" ::: "memory");                      \
        __builtin_amdgcn_sched_barrier(0);                                      \
        __builtin_amdgcn_s_setprio(1);                                          \
        _Pragma("unroll")                                                       \
        for (int kk = 0; kk < 2; ++kk)                                          \
            _Pragma("unroll")                                                   \
            for (int rf = 0; rf < 4; ++rf)                                      \
                _Pragma("unroll")                                               \
                for (int c = 0; c < 6; ++c)                                     \
                    acc[rf][c] = __builtin_amdgcn_mfma_f32_16x16x32_bf16(       \
                        af[kk][rf], bb[kk][c], acc[rf][c], 0, 0, 0);            \
        __builtin_amdgcn_s_setprio(0);                                          \
        __builtin_amdgcn_s_barrier();                                           \
        __builtin_amdgcn_sched_barrier(0);                                      \
    }

    for (int e = 0; e < 8; ++e) {
        BODY(2 * e,     xB0, xB1, xB2, xB3, xA0, xA1, xA2, xA3);
        BODY(2 * e + 1, xA0, xA1, xA2, xA3, xB0, xB1, xB2, xB3);
    }
#undef BODY
#undef STAGE
#undef LOADX

    // ---- epilogue: f16 partial write + sin partial ----
    _Float16* pb = part + (size_t)ks * 8192 * 384;
    const int lr4 = (lane >> 4) << 2;
    const int lc  = lane & 15;
#pragma unroll
    for (int rf = 0; rf < 4; ++rf)
#pragma unroll
        for (int c = 0; c < 6; ++c) {
            const int col = (ct0 + c) * 16 + lc;
#pragma unroll
            for (int i = 0; i < 4; ++i) {
                const int rl = rg * 64 + rf * 16 + lr4 + i;
                pb[(size_t)(row0 + rl) * 384 + col] = (_Float16)acc[rf][c][i];
            }
        }

    sinacc += __shfl_xor(sinacc, 1);
    sinacc += __shfl_xor(sinacc, 2);
    if ((t & 3) == 0)
        sinws[(size_t)ks * 8192 + row0 + srow] = sinacc;
}

// combine: sum 4 K-quarter partials, nonlinear terms + sin + beta -> out.
__global__ __launch_bounds__(512) void combine_kernel(const _Float16* __restrict__ part,
                                                      const float* __restrict__ sinws,
                                                      const float* __restrict__ C,
                                                      const float* __restrict__ beta,
                                                      const float* __restrict__ Csin,
                                                      float* __restrict__ out) {
    const int t   = threadIdx.x;
    const int row = blockIdx.x * 32 + (t >> 4);
    const int cc  = t & 15;
    const size_t rbase = (size_t)row * 384;

    float t1 = 0.f, t2 = 0.f, t3 = 0.f;
#pragma unroll
    for (int j = 0; j < 4; ++j) {
        const int c = j * 16 + cc;
        float a1 = 0.f, a2 = 0.f, b2 = 0.f, a3 = 0.f, b3 = 0.f, c3 = 0.f;
#pragma unroll
        for (int q = 0; q < 4; ++q) {
            const _Float16* p = part + (size_t)q * 8192 * 384 + rbase;
            a1 += (float)p[c];
            a2 += (float)p[64 + c];
            b2 += (float)p[128 + c];
            a3 += (float)p[192 + c];
            b3 += (float)p[256 + c];
            c3 += (float)p[320 + c];
        }
        t1 += a1;
        t2 += a2 * b2;
        t3 += a3 * b3 * c3;
    }
#pragma unroll
    for (int off = 1; off < 16; off <<= 1) {
        t1 += __shfl_xor(t1, off, 16);
        t2 += __shfl_xor(t2, off, 16);
        t3 += __shfl_xor(t3, off, 16);
    }
    if (cc == 0) {
        const float s = sinws[row] + sinws[8192 + row]
                      + sinws[2 * 8192 + row] + sinws[3 * 8192 + row];
        out[row] = beta[0] + C[0] * t1 + C[1] * t2 + C[2] * t3 + Csin[0] * s;
    }
}

extern "C" void kernel_launch(void* const* d_in, const int* in_sizes, int n_in,
                              void* d_out, int out_size, void* d_ws, size_t ws_size,
                              hipStream_t stream) {
    const float* X   = (const float*)d_in[0];
    const float* U1  = (const float*)d_in[1];
    const float* U2  = (const float*)d_in[2];
    const float* U3  = (const float*)d_in[3];
    const float* Cc  = (const float*)d_in[4];
    const float* bet = (const float*)d_in[5];
    const float* Cs  = (const float*)d_in[6];
    float* out = (float*)d_out;

    unsigned short* W = (unsigned short*)d_ws;                  // 3 MiB, frag-packed
    float* sinws = (float*)((char*)d_ws + SINW_OFF);            // 128 KiB
    _Float16* part = (_Float16*)((char*)d_ws + PART_OFF);       // 24 MiB

    reg_init_kernel<<<1, 64, 0, stream>>>(Cc, Cs, out + 8192);
    build_w_kernel<<<128 * NT, 64, 0, stream>>>(U1, U2, U3, W, out + 8192);
    poly_main_kernel<<<256, 512, 0, stream>>>(X, W, part, sinws);
    combine_kernel<<<256, 512, 0, stream>>>(part, sinws, Cc, bet, Cs, out);
}